// Round 1
// baseline (312.099 us; speedup 1.0000x reference)
//
#include <hip/hip_runtime.h>
#include <math.h>

#define NN 100000   // nodes
#define NE 1600000  // edges
#define NF 128      // in features
#define NC 16       // classes

// ---------------- degree / normalization ----------------

__global__ void k_init_deg(int* __restrict__ deg) {
    int n = blockIdx.x * 256 + threadIdx.x;
    if (n < NN) deg[n] = 1;  // self-loop
}

__global__ void k_count(const int* __restrict__ row, int* __restrict__ deg) {
    int e = blockIdx.x * 256 + threadIdx.x;
    if (e < NE) atomicAdd(&deg[row[e]], 1);
}

__global__ void k_dinv(const int* __restrict__ deg, float* __restrict__ dinv) {
    int n = blockIdx.x * 256 + threadIdx.x;
    if (n < NN) dinv[n] = rsqrtf((float)deg[n]);
}

__global__ void k_wgt(const int* __restrict__ row, const int* __restrict__ col,
                      const float* __restrict__ dinv, float* __restrict__ wgt) {
    int e = blockIdx.x * 256 + threadIdx.x;
    if (e < NE) wgt[e] = dinv[row[e]] * dinv[col[e]];
}

// ---------------- z = X @ W  (N x 128) @ (128 x 16) ----------------
// 256 threads/block, 64 rows/block. Each thread: 1 row x 4 cols.
#define GEMM_ROWS 64
#define XPAD (NF + 1)  // stride 129 -> LDS conflict-free

__global__ __launch_bounds__(256) void k_gemm(const float* __restrict__ x,
                                              const float* __restrict__ W,
                                              float* __restrict__ z) {
    __shared__ float Wl[NF * NC];           // 8 KB
    __shared__ float xs[GEMM_ROWS * XPAD];  // ~33 KB
    const int t = threadIdx.x;
    for (int i = t; i < NF * NC; i += 256) Wl[i] = W[i];
    const int rbase = blockIdx.x * GEMM_ROWS;
    for (int i = t; i < GEMM_ROWS * NF; i += 256) {
        int lrow = i / NF, k = i - lrow * NF;
        int r = rbase + lrow;
        xs[lrow * XPAD + k] = (r < NN) ? x[(size_t)r * NF + k] : 0.0f;
    }
    __syncthreads();
    const int lr = t >> 2;  // 0..63 local row
    const int cg = t & 3;   // col group (4 cols)
    float4 acc = make_float4(0.f, 0.f, 0.f, 0.f);
    #pragma unroll
    for (int k = 0; k < NF; ++k) {
        float xv = xs[lr * XPAD + k];
        float4 w = *(const float4*)&Wl[k * NC + cg * 4];
        acc.x = fmaf(xv, w.x, acc.x);
        acc.y = fmaf(xv, w.y, acc.y);
        acc.z = fmaf(xv, w.z, acc.z);
        acc.w = fmaf(xv, w.w, acc.w);
    }
    int r = rbase + lr;
    if (r < NN) *(float4*)&z[r * NC + cg * 4] = acc;
}

// ---------------- propagation ----------------
// dst[n][c] = dinv[n]^2 * src[n][c]   (self-loop term, also zero-inits dst)
__global__ void k_selfloop(const float* __restrict__ src, const float* __restrict__ dinv,
                           float* __restrict__ dst) {
    int i = blockIdx.x * 256 + threadIdx.x;  // over NN*NC (exact grid)
    int n = i >> 4;
    float d = dinv[n];
    dst[i] = d * d * src[i];
}

// dst[row[e]][c] += wgt[e] * src[col[e]][c] ; 16 lanes per edge
__global__ void k_hop(const int* __restrict__ row, const int* __restrict__ col,
                      const float* __restrict__ wgt, const float* __restrict__ src,
                      float* __restrict__ dst) {
    int t = blockIdx.x * 256 + threadIdx.x;  // over NE*NC (exact grid)
    int e = t >> 4;
    int c = t & 15;
    int r = row[e];
    int s = col[e];
    atomicAdd(&dst[r * NC + c], wgt[e] * src[s * NC + c]);
}

// ---------------- bias + log_softmax ----------------
__global__ void k_out(const float* __restrict__ h, const float* __restrict__ bias,
                      float* __restrict__ out) {
    int n = blockIdx.x * 256 + threadIdx.x;
    if (n >= NN) return;
    float v[NC];
    #pragma unroll
    for (int j = 0; j < NC / 4; ++j) {
        float4 q = *(const float4*)(h + n * NC + 4 * j);
        v[4 * j + 0] = q.x + bias[4 * j + 0];
        v[4 * j + 1] = q.y + bias[4 * j + 1];
        v[4 * j + 2] = q.z + bias[4 * j + 2];
        v[4 * j + 3] = q.w + bias[4 * j + 3];
    }
    float m = v[0];
    #pragma unroll
    for (int c = 1; c < NC; ++c) m = fmaxf(m, v[c]);
    float s = 0.f;
    #pragma unroll
    for (int c = 0; c < NC; ++c) s += expf(v[c] - m);
    float lse = m + logf(s);
    #pragma unroll
    for (int j = 0; j < NC / 4; ++j) {
        float4 q;
        q.x = v[4 * j + 0] - lse;
        q.y = v[4 * j + 1] - lse;
        q.z = v[4 * j + 2] - lse;
        q.w = v[4 * j + 3] - lse;
        *(float4*)(out + n * NC + 4 * j) = q;
    }
}

extern "C" void kernel_launch(void* const* d_in, const int* in_sizes, int n_in,
                              void* d_out, int out_size, void* d_ws, size_t ws_size,
                              hipStream_t stream) {
    const float* x    = (const float*)d_in[0];
    const int*   ei   = (const int*)d_in[1];   // [2, E] int32
    const float* W    = (const float*)d_in[2];
    const float* bias = (const float*)d_in[3];
    float* out = (float*)d_out;

    const int* row = ei;       // edge_index[0] (scatter destination)
    const int* col = ei + NE;  // edge_index[1] (gather source)

    // workspace carving (256B aligned); total ~20 MB
    char* ws = (char*)d_ws;
    size_t off = 0;
    auto carve = [&](size_t bytes) -> void* {
        void* p = ws + off;
        off += (bytes + 255) & ~(size_t)255;
        return p;
    };
    int*   deg  = (int*)  carve((size_t)NN * sizeof(int));
    float* dinv = (float*)carve((size_t)NN * sizeof(float));
    float* wgt  = (float*)carve((size_t)NE * sizeof(float));
    float* z    = (float*)carve((size_t)NN * NC * sizeof(float));
    float* h1   = (float*)carve((size_t)NN * NC * sizeof(float));

    k_init_deg<<<(NN + 255) / 256, 256, 0, stream>>>(deg);
    k_count<<<NE / 256, 256, 0, stream>>>(row, deg);
    k_dinv<<<(NN + 255) / 256, 256, 0, stream>>>(deg, dinv);
    k_wgt<<<NE / 256, 256, 0, stream>>>(row, col, dinv, wgt);

    // project first: z = X @ W  (propagation is linear, 8x less scatter work)
    k_gemm<<<(NN + GEMM_ROWS - 1) / GEMM_ROWS, 256, 0, stream>>>(x, W, z);

    // hop 1: h1 = S z
    k_selfloop<<<(NN * NC) / 256, 256, 0, stream>>>(z, dinv, h1);
    k_hop<<<((size_t)NE * NC) / 256, 256, 0, stream>>>(row, col, wgt, z, h1);

    // hop 2: z = S h1   (reuse z buffer)
    k_selfloop<<<(NN * NC) / 256, 256, 0, stream>>>(h1, dinv, z);
    k_hop<<<((size_t)NE * NC) / 256, 256, 0, stream>>>(row, col, wgt, h1, z);

    // logits + log_softmax
    k_out<<<(NN + 255) / 256, 256, 0, stream>>>(z, bias, out);
}

// Round 2
// 298.289 us; speedup vs baseline: 1.0463x; 1.0463x over previous
//
#include <hip/hip_runtime.h>
#include <math.h>

#define NN 100000   // nodes
#define NE 1600000  // edges
#define NF 128      // in features
#define NC 16       // classes
#define NB 391      // ceil(NN/256)

// ---------------- degree histogram ----------------

__global__ void k_zero(int* __restrict__ cnt) {
    int n = blockIdx.x * 256 + threadIdx.x;
    if (n < NN) cnt[n] = 0;
}

__global__ void k_count(const int* __restrict__ row, int* __restrict__ cnt) {
    int e = blockIdx.x * 256 + threadIdx.x;  // exact grid
    atomicAdd(&cnt[row[e]], 1);
}

__global__ void k_dinv(const int* __restrict__ cnt, float* __restrict__ dinv) {
    int n = blockIdx.x * 256 + threadIdx.x;
    if (n < NN) dinv[n] = rsqrtf((float)(cnt[n] + 1));  // +1 self-loop
}

// ---------------- 2-level exclusive scan of cnt -> rowptr ----------------

__global__ __launch_bounds__(256) void k_bsum(const int* __restrict__ cnt,
                                              int* __restrict__ bsum) {
    __shared__ int s[256];
    int t = threadIdx.x, i = blockIdx.x * 256 + t;
    s[t] = (i < NN) ? cnt[i] : 0;
    __syncthreads();
    for (int o = 128; o > 0; o >>= 1) {
        if (t < o) s[t] += s[t + o];
        __syncthreads();
    }
    if (t == 0) bsum[blockIdx.x] = s[0];
}

__global__ __launch_bounds__(512) void k_scanb(const int* __restrict__ bsum,
                                               int* __restrict__ boff) {
    __shared__ int s[512];
    int t = threadIdx.x;
    int v = (t < NB) ? bsum[t] : 0;
    s[t] = v;
    __syncthreads();
    for (int o = 1; o < 512; o <<= 1) {
        int a = (t >= o) ? s[t - o] : 0;
        __syncthreads();
        s[t] += a;
        __syncthreads();
    }
    if (t < NB) boff[t] = s[t] - v;  // exclusive
}

__global__ __launch_bounds__(256) void k_scanc(const int* __restrict__ cnt,
                                               const int* __restrict__ boff,
                                               int* __restrict__ rowptr,
                                               int* __restrict__ cursor) {
    __shared__ int s[256];
    int t = threadIdx.x, i = blockIdx.x * 256 + t;
    int v = (i < NN) ? cnt[i] : 0;
    s[t] = v;
    __syncthreads();
    for (int o = 1; o < 256; o <<= 1) {
        int a = (t >= o) ? s[t - o] : 0;
        __syncthreads();
        s[t] += a;
        __syncthreads();
    }
    if (i < NN) {
        int p = boff[blockIdx.x] + s[t] - v;  // exclusive prefix
        rowptr[i] = p;
        cursor[i] = p;
    }
}

// ---------------- CSR scatter: csr[pos] = (col, wgt) ----------------

__global__ void k_scatter(const int* __restrict__ row, const int* __restrict__ col,
                          const float* __restrict__ dinv, int* __restrict__ cursor,
                          int2* __restrict__ csr) {
    int e = blockIdx.x * 256 + threadIdx.x;  // exact grid
    int r = row[e], c = col[e];
    float w = dinv[r] * dinv[c];
    int pos = atomicAdd(&cursor[r], 1);
    csr[pos] = make_int2(c, __float_as_int(w));
}

// ---------------- z = X @ W ----------------
#define GEMM_ROWS 64
#define XPAD (NF + 4)  // 132: float4-alignable, LDS reads <=2-way (free)

__global__ __launch_bounds__(256) void k_gemm(const float* __restrict__ x,
                                              const float* __restrict__ W,
                                              float* __restrict__ z) {
    __shared__ float Wl[NF * NC];           // 8 KB
    __shared__ float xs[GEMM_ROWS * XPAD];  // 33 KB
    const int t = threadIdx.x;
    for (int i = t; i < NF * NC; i += 256) Wl[i] = W[i];
    const int rbase = blockIdx.x * GEMM_ROWS;
    const float4* x4 = (const float4*)x;
    for (int i = t; i < GEMM_ROWS * (NF / 4); i += 256) {
        int lrow = i / (NF / 4), k4 = i - lrow * (NF / 4);
        int r = rbase + lrow;
        float4 v = (r < NN) ? x4[(size_t)r * (NF / 4) + k4]
                            : make_float4(0.f, 0.f, 0.f, 0.f);
        *(float4*)&xs[lrow * XPAD + 4 * k4] = v;  // byte addr 16-aligned (528*lrow+16*k4)
    }
    __syncthreads();
    const int lr = t >> 2;
    const int cg = t & 3;
    float4 acc = make_float4(0.f, 0.f, 0.f, 0.f);
    #pragma unroll
    for (int k = 0; k < NF; ++k) {
        float xv = xs[lr * XPAD + k];
        float4 w = *(const float4*)&Wl[k * NC + cg * 4];
        acc.x = fmaf(xv, w.x, acc.x);
        acc.y = fmaf(xv, w.y, acc.y);
        acc.z = fmaf(xv, w.z, acc.z);
        acc.w = fmaf(xv, w.w, acc.w);
    }
    int r = rbase + lr;
    if (r < NN) *(float4*)&z[r * NC + cg * 4] = acc;
}

// ---------------- gather hops (no atomics) ----------------
// 16 lanes per node; lane c owns class c. acc = dinv^2*src[n] + sum_e w*src[col]

__global__ __launch_bounds__(256) void k_hop1(const int* __restrict__ rowptr,
                                              const int* __restrict__ cnt,
                                              const float* __restrict__ dinv,
                                              const int2* __restrict__ csr,
                                              const float* __restrict__ src,
                                              float* __restrict__ dst) {
    int t = blockIdx.x * 256 + threadIdx.x;  // exact grid NN*NC
    int n = t >> 4, c = t & 15;
    float d = dinv[n];
    float acc = d * d * src[n * NC + c];
    int s = rowptr[n], m = cnt[n];
    for (int i = 0; i < m; ++i) {
        int2 ew = csr[s + i];
        acc = fmaf(__int_as_float(ew.y), src[ew.x * NC + c], acc);
    }
    dst[n * NC + c] = acc;
}

// hop2 fused with bias + log_softmax (16-lane shuffle reduction)
__global__ __launch_bounds__(256) void k_hop2(const int* __restrict__ rowptr,
                                              const int* __restrict__ cnt,
                                              const float* __restrict__ dinv,
                                              const int2* __restrict__ csr,
                                              const float* __restrict__ src,
                                              const float* __restrict__ bias,
                                              float* __restrict__ out) {
    int t = blockIdx.x * 256 + threadIdx.x;  // exact grid NN*NC
    int n = t >> 4, c = t & 15;
    float d = dinv[n];
    float acc = d * d * src[n * NC + c];
    int s = rowptr[n], m = cnt[n];
    for (int i = 0; i < m; ++i) {
        int2 ew = csr[s + i];
        acc = fmaf(__int_as_float(ew.y), src[ew.x * NC + c], acc);
    }
    float v = acc + bias[c];
    float mx = v;
    #pragma unroll
    for (int o = 8; o > 0; o >>= 1) mx = fmaxf(mx, __shfl_xor(mx, o, 16));
    float ex = expf(v - mx);
    float sm = ex;
    #pragma unroll
    for (int o = 8; o > 0; o >>= 1) sm += __shfl_xor(sm, o, 16);
    out[n * NC + c] = v - mx - logf(sm);
}

extern "C" void kernel_launch(void* const* d_in, const int* in_sizes, int n_in,
                              void* d_out, int out_size, void* d_ws, size_t ws_size,
                              hipStream_t stream) {
    const float* x    = (const float*)d_in[0];
    const int*   ei   = (const int*)d_in[1];
    const float* W    = (const float*)d_in[2];
    const float* bias = (const float*)d_in[3];
    float* out = (float*)d_out;

    const int* row = ei;       // destinations (scatter index in reference)
    const int* col = ei + NE;  // sources

    char* ws = (char*)d_ws;
    size_t off = 0;
    auto carve = [&](size_t bytes) -> void* {
        void* p = ws + off;
        off += (bytes + 255) & ~(size_t)255;
        return p;
    };
    int*   cnt    = (int*)  carve((size_t)NN * sizeof(int));
    float* dinv   = (float*)carve((size_t)NN * sizeof(float));
    int*   rowptr = (int*)  carve((size_t)NN * sizeof(int));
    int*   cursor = (int*)  carve((size_t)NN * sizeof(int));
    int*   bsum   = (int*)  carve((size_t)NB * sizeof(int));
    int*   boff   = (int*)  carve((size_t)NB * sizeof(int));
    int2*  csr    = (int2*) carve((size_t)NE * sizeof(int2));   // 12.8 MB
    float* z      = (float*)carve((size_t)NN * NC * sizeof(float));
    float* h1     = (float*)carve((size_t)NN * NC * sizeof(float));

    k_zero <<<NB, 256, 0, stream>>>(cnt);
    k_count<<<NE / 256, 256, 0, stream>>>(row, cnt);
    k_dinv <<<NB, 256, 0, stream>>>(cnt, dinv);
    k_bsum <<<NB, 256, 0, stream>>>(cnt, bsum);
    k_scanb<<<1, 512, 0, stream>>>(bsum, boff);
    k_scanc<<<NB, 256, 0, stream>>>(cnt, boff, rowptr, cursor);
    k_scatter<<<NE / 256, 256, 0, stream>>>(row, col, dinv, cursor, csr);

    k_gemm<<<(NN + GEMM_ROWS - 1) / GEMM_ROWS, 256, 0, stream>>>(x, W, z);

    k_hop1<<<(NN * NC) / 256, 256, 0, stream>>>(rowptr, cnt, dinv, csr, z, h1);
    k_hop2<<<(NN * NC) / 256, 256, 0, stream>>>(rowptr, cnt, dinv, csr, h1, bias, out);
}

// Round 3
// 286.878 us; speedup vs baseline: 1.0879x; 1.0398x over previous
//
#include <hip/hip_runtime.h>
#include <math.h>

#define NN 100000   // nodes
#define NE 1600000  // edges
#define NF 128      // in features
#define NC 16       // classes
#define NB 391      // ceil(NN/256)

// ---------------- degree histogram ----------------

__global__ void k_zero(int* __restrict__ cnt) {
    int n = blockIdx.x * 256 + threadIdx.x;
    if (n < NN) cnt[n] = 0;
}

// 4 edges/thread, coalesced int4 loads, fire-and-forget atomics
__global__ void k_count(const int* __restrict__ row, int* __restrict__ cnt) {
    int base = (blockIdx.x * 256 + threadIdx.x) * 4;
    if (base >= NE) return;
    int4 r4 = *(const int4*)&row[base];
    atomicAdd(&cnt[r4.x], 1);
    atomicAdd(&cnt[r4.y], 1);
    atomicAdd(&cnt[r4.z], 1);
    atomicAdd(&cnt[r4.w], 1);
}

__global__ void k_dinv(const int* __restrict__ cnt, float* __restrict__ dinv) {
    int n = blockIdx.x * 256 + threadIdx.x;
    if (n < NN) dinv[n] = rsqrtf((float)(cnt[n] + 1));  // +1 self-loop
}

// ---------------- 2-level exclusive scan of cnt -> rowptr ----------------

__global__ __launch_bounds__(256) void k_bsum(const int* __restrict__ cnt,
                                              int* __restrict__ bsum) {
    __shared__ int s[256];
    int t = threadIdx.x, i = blockIdx.x * 256 + t;
    s[t] = (i < NN) ? cnt[i] : 0;
    __syncthreads();
    for (int o = 128; o > 0; o >>= 1) {
        if (t < o) s[t] += s[t + o];
        __syncthreads();
    }
    if (t == 0) bsum[blockIdx.x] = s[0];
}

__global__ __launch_bounds__(512) void k_scanb(const int* __restrict__ bsum,
                                               int* __restrict__ boff) {
    __shared__ int s[512];
    int t = threadIdx.x;
    int v = (t < NB) ? bsum[t] : 0;
    s[t] = v;
    __syncthreads();
    for (int o = 1; o < 512; o <<= 1) {
        int a = (t >= o) ? s[t - o] : 0;
        __syncthreads();
        s[t] += a;
        __syncthreads();
    }
    if (t < NB) boff[t] = s[t] - v;  // exclusive
}

__global__ __launch_bounds__(256) void k_scanc(const int* __restrict__ cnt,
                                               const int* __restrict__ boff,
                                               int* __restrict__ rowptr,
                                               int* __restrict__ cursor) {
    __shared__ int s[256];
    int t = threadIdx.x, i = blockIdx.x * 256 + t;
    int v = (i < NN) ? cnt[i] : 0;
    s[t] = v;
    __syncthreads();
    for (int o = 1; o < 256; o <<= 1) {
        int a = (t >= o) ? s[t - o] : 0;
        __syncthreads();
        s[t] += a;
        __syncthreads();
    }
    if (i < NN) {
        int p = boff[blockIdx.x] + s[t] - v;
        rowptr[i] = p;
        cursor[i] = p;
    }
}

// ---------------- CSR scatter: csr[pos] = col  (4B payload, no weights) ----
// 4 edges/thread: 4 independent atomic->store chains; all waves co-resident.

__global__ void k_scatter(const int* __restrict__ row, const int* __restrict__ col,
                          int* __restrict__ cursor, int* __restrict__ csr) {
    int base = (blockIdx.x * 256 + threadIdx.x) * 4;
    if (base >= NE) return;
    int4 r4 = *(const int4*)&row[base];
    int4 c4 = *(const int4*)&col[base];
    int p0 = atomicAdd(&cursor[r4.x], 1);
    int p1 = atomicAdd(&cursor[r4.y], 1);
    int p2 = atomicAdd(&cursor[r4.z], 1);
    int p3 = atomicAdd(&cursor[r4.w], 1);
    csr[p0] = c4.x;
    csr[p1] = c4.y;
    csr[p2] = c4.z;
    csr[p3] = c4.w;
}

// ---------------- u = dinv * (X @ W)  (scaled projection) ----------------
#define GEMM_ROWS 64
#define XPAD (NF + 4)

__global__ __launch_bounds__(256) void k_gemm(const float* __restrict__ x,
                                              const float* __restrict__ W,
                                              const float* __restrict__ dinv,
                                              float* __restrict__ u) {
    __shared__ float Wl[NF * NC];
    __shared__ float xs[GEMM_ROWS * XPAD];
    const int t = threadIdx.x;
    for (int i = t; i < NF * NC; i += 256) Wl[i] = W[i];
    const int rbase = blockIdx.x * GEMM_ROWS;
    const float4* x4 = (const float4*)x;
    for (int i = t; i < GEMM_ROWS * (NF / 4); i += 256) {
        int lrow = i / (NF / 4), k4 = i - lrow * (NF / 4);
        int r = rbase + lrow;
        float4 v = (r < NN) ? x4[(size_t)r * (NF / 4) + k4]
                            : make_float4(0.f, 0.f, 0.f, 0.f);
        *(float4*)&xs[lrow * XPAD + 4 * k4] = v;
    }
    __syncthreads();
    const int lr = t >> 2;
    const int cg = t & 3;
    float4 acc = make_float4(0.f, 0.f, 0.f, 0.f);
    #pragma unroll
    for (int k = 0; k < NF; ++k) {
        float xv = xs[lr * XPAD + k];
        float4 w = *(const float4*)&Wl[k * NC + cg * 4];
        acc.x = fmaf(xv, w.x, acc.x);
        acc.y = fmaf(xv, w.y, acc.y);
        acc.z = fmaf(xv, w.z, acc.z);
        acc.w = fmaf(xv, w.w, acc.w);
    }
    int r = rbase + lr;
    if (r < NN) {
        float d = dinv[r];
        acc.x *= d; acc.y *= d; acc.z *= d; acc.w *= d;
        *(float4*)&u[r * NC + cg * 4] = acc;
    }
}

// ---------------- gather hops (no atomics, no weights) ----------------
// 16 lanes/node. sum = u[n] + sum_{s in in(n)} u[s]; out scaled by d^2 (hop1
// feeds hop2 with u1 = dinv * h1) or d + bias + log_softmax (hop2).

__global__ __launch_bounds__(256) void k_hop1(const int* __restrict__ rowptr,
                                              const int* __restrict__ cnt,
                                              const float* __restrict__ dinv,
                                              const int* __restrict__ csr,
                                              const float* __restrict__ u,
                                              float* __restrict__ u1) {
    int t = blockIdx.x * 256 + threadIdx.x;  // exact grid NN*NC
    int n = t >> 4, c = t & 15;
    int s = rowptr[n], m = cnt[n];
    float acc = u[(n << 4) + c];
    int i = 0;
    for (; i + 4 <= m; i += 4) {
        int c0 = csr[s + i], c1 = csr[s + i + 1];
        int c2 = csr[s + i + 2], c3 = csr[s + i + 3];
        float a0 = u[(c0 << 4) + c], a1 = u[(c1 << 4) + c];
        float a2 = u[(c2 << 4) + c], a3 = u[(c3 << 4) + c];
        acc += (a0 + a1) + (a2 + a3);
    }
    for (; i < m; ++i) acc += u[(csr[s + i] << 4) + c];
    float d = dinv[n];
    u1[t] = d * d * acc;
}

__global__ __launch_bounds__(256) void k_hop2(const int* __restrict__ rowptr,
                                              const int* __restrict__ cnt,
                                              const float* __restrict__ dinv,
                                              const int* __restrict__ csr,
                                              const float* __restrict__ u1,
                                              const float* __restrict__ bias,
                                              float* __restrict__ out) {
    int t = blockIdx.x * 256 + threadIdx.x;  // exact grid NN*NC
    int n = t >> 4, c = t & 15;
    int s = rowptr[n], m = cnt[n];
    float acc = u1[(n << 4) + c];
    int i = 0;
    for (; i + 4 <= m; i += 4) {
        int c0 = csr[s + i], c1 = csr[s + i + 1];
        int c2 = csr[s + i + 2], c3 = csr[s + i + 3];
        float a0 = u1[(c0 << 4) + c], a1 = u1[(c1 << 4) + c];
        float a2 = u1[(c2 << 4) + c], a3 = u1[(c3 << 4) + c];
        acc += (a0 + a1) + (a2 + a3);
    }
    for (; i < m; ++i) acc += u1[(csr[s + i] << 4) + c];
    float v = dinv[n] * acc + bias[c];
    float mx = v;
    #pragma unroll
    for (int o = 8; o > 0; o >>= 1) mx = fmaxf(mx, __shfl_xor(mx, o, 16));
    float ex = expf(v - mx);
    float sm = ex;
    #pragma unroll
    for (int o = 8; o > 0; o >>= 1) sm += __shfl_xor(sm, o, 16);
    out[t] = v - mx - logf(sm);
}

extern "C" void kernel_launch(void* const* d_in, const int* in_sizes, int n_in,
                              void* d_out, int out_size, void* d_ws, size_t ws_size,
                              hipStream_t stream) {
    const float* x    = (const float*)d_in[0];
    const int*   ei   = (const int*)d_in[1];
    const float* W    = (const float*)d_in[2];
    const float* bias = (const float*)d_in[3];
    float* out = (float*)d_out;

    const int* row = ei;       // destinations
    const int* col = ei + NE;  // sources

    char* ws = (char*)d_ws;
    size_t off = 0;
    auto carve = [&](size_t bytes) -> void* {
        void* p = ws + off;
        off += (bytes + 255) & ~(size_t)255;
        return p;
    };
    int*   cnt    = (int*)  carve((size_t)NN * sizeof(int));
    float* dinv   = (float*)carve((size_t)NN * sizeof(float));
    int*   rowptr = (int*)  carve((size_t)NN * sizeof(int));
    int*   cursor = (int*)  carve((size_t)NN * sizeof(int));
    int*   bsum   = (int*)  carve((size_t)NB * sizeof(int));
    int*   boff   = (int*)  carve((size_t)NB * sizeof(int));
    int*   csr    = (int*)  carve((size_t)NE * sizeof(int));    // 6.4 MB
    float* u      = (float*)carve((size_t)NN * NC * sizeof(float));
    float* u1     = (float*)carve((size_t)NN * NC * sizeof(float));

    const int EB4 = (NE / 4 + 255) / 256;  // 1563 blocks for 4-edge/thread kernels

    k_zero   <<<NB, 256, 0, stream>>>(cnt);
    k_count  <<<EB4, 256, 0, stream>>>(row, cnt);
    k_dinv   <<<NB, 256, 0, stream>>>(cnt, dinv);
    k_bsum   <<<NB, 256, 0, stream>>>(cnt, bsum);
    k_scanb  <<<1, 512, 0, stream>>>(bsum, boff);
    k_scanc  <<<NB, 256, 0, stream>>>(cnt, boff, rowptr, cursor);
    k_scatter<<<EB4, 256, 0, stream>>>(row, col, cursor, csr);

    k_gemm<<<(NN + GEMM_ROWS - 1) / GEMM_ROWS, 256, 0, stream>>>(x, W, dinv, u);

    k_hop1<<<(NN * NC) / 256, 256, 0, stream>>>(rowptr, cnt, dinv, csr, u, u1);
    k_hop2<<<(NN * NC) / 256, 256, 0, stream>>>(rowptr, cnt, dinv, csr, u1, bias, out);
}

// Round 4
// 267.451 us; speedup vs baseline: 1.1669x; 1.0726x over previous
//
#include <hip/hip_runtime.h>
#include <math.h>

#define NN 100000   // nodes
#define NE 1600000  // edges
#define NF 128      // in features
#define NC 16       // classes
#define NB 391      // ceil(NN/256)
#define NBUK 49     // buckets = ceil(NN/2048)
#define BSH 11      // bucket = row >> 11
#define CHUNK 4096  // edges per partition block
#define P1B 391     // ceil(NE/CHUNK)

// ---------------- zero counters ----------------
__global__ void k_zero(int* __restrict__ cnt, int* __restrict__ bcnt) {
    int n = blockIdx.x * 256 + threadIdx.x;
    if (n < NN) cnt[n] = 0;
    if (n < NBUK) bcnt[n] = 0;
}

// ---------------- degree histogram (4 edges/thread, NT loads) -------------
__global__ void k_count(const int* __restrict__ row, int* __restrict__ cnt) {
    int base = (blockIdx.x * 256 + threadIdx.x) * 4;
    if (base >= NE) return;
    int r0 = __builtin_nontemporal_load(row + base);
    int r1 = __builtin_nontemporal_load(row + base + 1);
    int r2 = __builtin_nontemporal_load(row + base + 2);
    int r3 = __builtin_nontemporal_load(row + base + 3);
    atomicAdd(&cnt[r0], 1);
    atomicAdd(&cnt[r1], 1);
    atomicAdd(&cnt[r2], 1);
    atomicAdd(&cnt[r3], 1);
}

__global__ void k_dinv(const int* __restrict__ cnt, float* __restrict__ dinv) {
    int n = blockIdx.x * 256 + threadIdx.x;
    if (n < NN) dinv[n] = rsqrtf((float)(cnt[n] + 1));  // +1 self-loop
}

// ---------------- 2-level exclusive scan of cnt -> rowptr ----------------
__global__ __launch_bounds__(256) void k_bsum(const int* __restrict__ cnt,
                                              int* __restrict__ bsum) {
    __shared__ int s[256];
    int t = threadIdx.x, i = blockIdx.x * 256 + t;
    s[t] = (i < NN) ? cnt[i] : 0;
    __syncthreads();
    for (int o = 128; o > 0; o >>= 1) {
        if (t < o) s[t] += s[t + o];
        __syncthreads();
    }
    if (t == 0) bsum[blockIdx.x] = s[0];
}

__global__ __launch_bounds__(512) void k_scanb(const int* __restrict__ bsum,
                                               int* __restrict__ boff) {
    __shared__ int s[512];
    int t = threadIdx.x;
    int v = (t < NB) ? bsum[t] : 0;
    s[t] = v;
    __syncthreads();
    for (int o = 1; o < 512; o <<= 1) {
        int a = (t >= o) ? s[t - o] : 0;
        __syncthreads();
        s[t] += a;
        __syncthreads();
    }
    if (t < NB) boff[t] = s[t] - v;  // exclusive
}

__global__ __launch_bounds__(256) void k_scanc(const int* __restrict__ cnt,
                                               const int* __restrict__ boff,
                                               int* __restrict__ rowptr) {
    __shared__ int s[256];
    int t = threadIdx.x, i = blockIdx.x * 256 + t;
    int v = (i < NN) ? cnt[i] : 0;
    s[t] = v;
    __syncthreads();
    for (int o = 1; o < 256; o <<= 1) {
        int a = (t >= o) ? s[t - o] : 0;
        __syncthreads();
        s[t] += a;
        __syncthreads();
    }
    if (i < NN) rowptr[i] = boff[blockIdx.x] + s[t] - v;  // exclusive prefix
}

// ---------------- P0: bucket histogram ----------------
__global__ __launch_bounds__(256) void k_bhist(const int* __restrict__ row,
                                               int* __restrict__ bcnt) {
    __shared__ int h[NBUK];
    int t = threadIdx.x;
    if (t < NBUK) h[t] = 0;
    __syncthreads();
    int base = (blockIdx.x * 256 + t) * 4;
    if (base < NE) {
        int r0 = __builtin_nontemporal_load(row + base);
        int r1 = __builtin_nontemporal_load(row + base + 1);
        int r2 = __builtin_nontemporal_load(row + base + 2);
        int r3 = __builtin_nontemporal_load(row + base + 3);
        atomicAdd(&h[r0 >> BSH], 1);
        atomicAdd(&h[r1 >> BSH], 1);
        atomicAdd(&h[r2 >> BSH], 1);
        atomicAdd(&h[r3 >> BSH], 1);
    }
    __syncthreads();
    if (t < NBUK && h[t] > 0) atomicAdd(&bcnt[t], h[t]);
}

// ---------------- tiny bucket scan ----------------
__global__ void k_bscan(const int* __restrict__ bcnt, int* __restrict__ bbase,
                        int* __restrict__ bcur) {
    if (threadIdx.x == 0) {
        int acc = 0;
        for (int i = 0; i < NBUK; ++i) {
            bbase[i] = acc;
            bcur[i] = acc;
            acc += bcnt[i];
        }
    }
}

// ---------------- P1: partition edges into bucket-grouped pairs ----------
__global__ __launch_bounds__(256) void k_part(const int* __restrict__ row,
                                              const int* __restrict__ col,
                                              int* __restrict__ bcur,
                                              int2* __restrict__ pairs) {
    __shared__ int hist[NBUK];
    __shared__ int loff[NBUK];
    __shared__ int gbase[NBUK];
    __shared__ int2 stage[CHUNK];          // 32 KB
    __shared__ unsigned char bkt[CHUNK];   // 4 KB
    const int t = threadIdx.x;
    const int cb = blockIdx.x * CHUNK;
    const int ccnt = min(CHUNK, NE - cb);
    const int nquad = ccnt >> 2;
    if (t < NBUK) hist[t] = 0;
    __syncthreads();

    int rr[16], cc[16], rk[16];
    #pragma unroll
    for (int j = 0; j < 4; ++j) {
        int q = j * 256 + t;
        if (q < nquad) {
            int4 r4 = *(const int4*)&row[cb + 4 * q];
            int4 c4 = *(const int4*)&col[cb + 4 * q];
            rr[4 * j] = r4.x; rr[4 * j + 1] = r4.y; rr[4 * j + 2] = r4.z; rr[4 * j + 3] = r4.w;
            cc[4 * j] = c4.x; cc[4 * j + 1] = c4.y; cc[4 * j + 2] = c4.z; cc[4 * j + 3] = c4.w;
            #pragma unroll
            for (int k = 0; k < 4; ++k)
                rk[4 * j + k] = atomicAdd(&hist[rr[4 * j + k] >> BSH], 1);
        }
    }
    __syncthreads();
    if (t == 0) {  // exclusive scan over 49 buckets
        int acc = 0;
        for (int i = 0; i < NBUK; ++i) { loff[i] = acc; acc += hist[i]; }
    }
    __syncthreads();
    if (t < NBUK && hist[t] > 0) gbase[t] = atomicAdd(&bcur[t], hist[t]);
    __syncthreads();
    #pragma unroll
    for (int j = 0; j < 4; ++j) {
        int q = j * 256 + t;
        if (q < nquad) {
            #pragma unroll
            for (int k = 0; k < 4; ++k) {
                int b = rr[4 * j + k] >> BSH;
                int pos = loff[b] + rk[4 * j + k];
                stage[pos] = make_int2(rr[4 * j + k], cc[4 * j + k]);
                bkt[pos] = (unsigned char)b;
            }
        }
    }
    __syncthreads();
    for (int s = t; s < ccnt; s += 256) {
        int b = bkt[s];
        pairs[gbase[b] + (s - loff[b])] = stage[s];
    }
}

// ---------------- P2: per-bucket fine counting-scatter -> csr ------------
// One block per bucket; stores confined to ~130KB window => L2-merged.
__global__ __launch_bounds__(1024) void k_fine(const int* __restrict__ rowptr,
                                               const int* __restrict__ bbase,
                                               const int* __restrict__ bcnt,
                                               const int2* __restrict__ pairs,
                                               int* __restrict__ csr) {
    __shared__ int cur[1 << BSH];  // 2048 cursors, 8 KB
    const int b = blockIdx.x;
    const int nb = b << BSH;
    const int t = threadIdx.x;
    for (int i = t; i < (1 << BSH); i += 1024) {
        int nd = nb + i;
        cur[i] = (nd < NN) ? rowptr[nd] : 0;
    }
    __syncthreads();
    const int st = bbase[b];
    const int en = st + bcnt[b];
    for (int e = st + t; e < en; e += 1024) {
        int2 p = pairs[e];
        int pos = atomicAdd(&cur[p.x - nb], 1);
        csr[pos] = p.y;
    }
}

// ---------------- u = dinv * (X @ W) ----------------
#define GEMM_ROWS 64
#define XPAD (NF + 4)

__global__ __launch_bounds__(256) void k_gemm(const float* __restrict__ x,
                                              const float* __restrict__ W,
                                              const float* __restrict__ dinv,
                                              float* __restrict__ u) {
    __shared__ float Wl[NF * NC];
    __shared__ float xs[GEMM_ROWS * XPAD];
    const int t = threadIdx.x;
    for (int i = t; i < NF * NC; i += 256) Wl[i] = W[i];
    const int rbase = blockIdx.x * GEMM_ROWS;
    const float4* x4 = (const float4*)x;
    for (int i = t; i < GEMM_ROWS * (NF / 4); i += 256) {
        int lrow = i / (NF / 4), k4 = i - lrow * (NF / 4);
        int r = rbase + lrow;
        float4 v = (r < NN) ? x4[(size_t)r * (NF / 4) + k4]
                            : make_float4(0.f, 0.f, 0.f, 0.f);
        *(float4*)&xs[lrow * XPAD + 4 * k4] = v;
    }
    __syncthreads();
    const int lr = t >> 2;
    const int cg = t & 3;
    float4 acc = make_float4(0.f, 0.f, 0.f, 0.f);
    #pragma unroll
    for (int k = 0; k < NF; ++k) {
        float xv = xs[lr * XPAD + k];
        float4 w = *(const float4*)&Wl[k * NC + cg * 4];
        acc.x = fmaf(xv, w.x, acc.x);
        acc.y = fmaf(xv, w.y, acc.y);
        acc.z = fmaf(xv, w.z, acc.z);
        acc.w = fmaf(xv, w.w, acc.w);
    }
    int r = rbase + lr;
    if (r < NN) {
        float d = dinv[r];
        acc.x *= d; acc.y *= d; acc.z *= d; acc.w *= d;
        *(float4*)&u[r * NC + cg * 4] = acc;
    }
}

// ---------------- gather hops (no atomics, no weights) ----------------
// 16 lanes/node; lane c owns class c. 8-deep unroll; NT on csr stream.

__global__ __launch_bounds__(256) void k_hop1(const int* __restrict__ rowptr,
                                              const int* __restrict__ cnt,
                                              const float* __restrict__ dinv,
                                              const int* __restrict__ csr,
                                              const float* __restrict__ u,
                                              float* __restrict__ u1) {
    int t = blockIdx.x * 256 + threadIdx.x;  // exact grid NN*NC
    int n = t >> 4, c = t & 15;
    int s = rowptr[n], m = cnt[n];
    float acc = u[(n << 4) + c];
    int i = 0;
    for (; i + 8 <= m; i += 8) {
        int cc[8];
        #pragma unroll
        for (int j = 0; j < 8; ++j) cc[j] = __builtin_nontemporal_load(&csr[s + i + j]);
        float a0 = u[(cc[0] << 4) + c], a1 = u[(cc[1] << 4) + c];
        float a2 = u[(cc[2] << 4) + c], a3 = u[(cc[3] << 4) + c];
        float a4 = u[(cc[4] << 4) + c], a5 = u[(cc[5] << 4) + c];
        float a6 = u[(cc[6] << 4) + c], a7 = u[(cc[7] << 4) + c];
        acc += ((a0 + a1) + (a2 + a3)) + ((a4 + a5) + (a6 + a7));
    }
    for (; i < m; ++i) acc += u[(__builtin_nontemporal_load(&csr[s + i]) << 4) + c];
    float d = dinv[n];
    u1[t] = d * d * acc;
}

__global__ __launch_bounds__(256) void k_hop2(const int* __restrict__ rowptr,
                                              const int* __restrict__ cnt,
                                              const float* __restrict__ dinv,
                                              const int* __restrict__ csr,
                                              const float* __restrict__ u1,
                                              const float* __restrict__ bias,
                                              float* __restrict__ out) {
    int t = blockIdx.x * 256 + threadIdx.x;  // exact grid NN*NC
    int n = t >> 4, c = t & 15;
    int s = rowptr[n], m = cnt[n];
    float acc = u1[(n << 4) + c];
    int i = 0;
    for (; i + 8 <= m; i += 8) {
        int cc[8];
        #pragma unroll
        for (int j = 0; j < 8; ++j) cc[j] = __builtin_nontemporal_load(&csr[s + i + j]);
        float a0 = u1[(cc[0] << 4) + c], a1 = u1[(cc[1] << 4) + c];
        float a2 = u1[(cc[2] << 4) + c], a3 = u1[(cc[3] << 4) + c];
        float a4 = u1[(cc[4] << 4) + c], a5 = u1[(cc[5] << 4) + c];
        float a6 = u1[(cc[6] << 4) + c], a7 = u1[(cc[7] << 4) + c];
        acc += ((a0 + a1) + (a2 + a3)) + ((a4 + a5) + (a6 + a7));
    }
    for (; i < m; ++i) acc += u1[(__builtin_nontemporal_load(&csr[s + i]) << 4) + c];
    float v = dinv[n] * acc + bias[c];
    float mx = v;
    #pragma unroll
    for (int o = 8; o > 0; o >>= 1) mx = fmaxf(mx, __shfl_xor(mx, o, 16));
    float ex = expf(v - mx);
    float sm = ex;
    #pragma unroll
    for (int o = 8; o > 0; o >>= 1) sm += __shfl_xor(sm, o, 16);
    out[t] = v - mx - logf(sm);
}

extern "C" void kernel_launch(void* const* d_in, const int* in_sizes, int n_in,
                              void* d_out, int out_size, void* d_ws, size_t ws_size,
                              hipStream_t stream) {
    const float* x    = (const float*)d_in[0];
    const int*   ei   = (const int*)d_in[1];
    const float* W    = (const float*)d_in[2];
    const float* bias = (const float*)d_in[3];
    float* out = (float*)d_out;

    const int* row = ei;       // destinations
    const int* col = ei + NE;  // sources

    char* ws = (char*)d_ws;
    size_t off = 0;
    auto carve = [&](size_t bytes) -> void* {
        void* p = ws + off;
        off += (bytes + 255) & ~(size_t)255;
        return p;
    };
    int*   cnt    = (int*)  carve((size_t)NN * sizeof(int));
    float* dinv   = (float*)carve((size_t)NN * sizeof(float));
    int*   rowptr = (int*)  carve((size_t)NN * sizeof(int));
    int*   bsum   = (int*)  carve((size_t)NB * sizeof(int));
    int*   boff   = (int*)  carve((size_t)NB * sizeof(int));
    int*   bcnt   = (int*)  carve((size_t)NBUK * sizeof(int));
    int*   bbase  = (int*)  carve((size_t)NBUK * sizeof(int));
    int*   bcur   = (int*)  carve((size_t)NBUK * sizeof(int));
    int2*  pairs  = (int2*) carve((size_t)NE * sizeof(int2));   // 12.8 MB
    int*   csr    = (int*)  carve((size_t)NE * sizeof(int));    // 6.4 MB
    // u / u1 alias pairs (dead after k_fine; gemm runs after)
    float* u  = (float*)pairs;
    float* u1 = (float*)pairs + (size_t)NN * NC;

    const int EB4 = (NE / 4 + 255) / 256;

    k_zero <<<NB, 256, 0, stream>>>(cnt, bcnt);
    k_count<<<EB4, 256, 0, stream>>>(row, cnt);
    k_dinv <<<NB, 256, 0, stream>>>(cnt, dinv);
    k_bsum <<<NB, 256, 0, stream>>>(cnt, bsum);
    k_scanb<<<1, 512, 0, stream>>>(bsum, boff);
    k_scanc<<<NB, 256, 0, stream>>>(cnt, boff, rowptr);
    k_bhist<<<EB4, 256, 0, stream>>>(row, bcnt);
    k_bscan<<<1, 64, 0, stream>>>(bcnt, bbase, bcur);
    k_part <<<P1B, 256, 0, stream>>>(row, col, bcur, pairs);
    k_fine <<<NBUK, 1024, 0, stream>>>(rowptr, bbase, bcnt, pairs, csr);

    k_gemm<<<(NN + GEMM_ROWS - 1) / GEMM_ROWS, 256, 0, stream>>>(x, W, dinv, u);

    k_hop1<<<(NN * NC) / 256, 256, 0, stream>>>(rowptr, cnt, dinv, csr, u, u1);
    k_hop2<<<(NN * NC) / 256, 256, 0, stream>>>(rowptr, cnt, dinv, csr, u1, bias, out);
}

// Round 5
// 175.271 us; speedup vs baseline: 1.7807x; 1.5259x over previous
//
#include <hip/hip_runtime.h>
#include <math.h>

#define NN 100000   // nodes
#define NE 1600000  // edges
#define NF 128      // in features
#define NC 16       // classes
#define NBUK 49     // buckets = ceil(NN/2048)
#define BSH 11      // bucket = row >> 11
#define BNODES (1 << BSH)
#define CHUNK 4096  // edges per partition block
#define P1B 391     // ceil(NE/CHUNK)

// ---------------- zero bucket counters ----------------
__global__ void k_zero(int* __restrict__ bcnt) {
    int n = threadIdx.x;
    if (n < NBUK) bcnt[n] = 0;
}

// ---------------- P0: bucket histogram (16 edges/thread) ----------------
__global__ __launch_bounds__(256) void k_bhist(const int* __restrict__ row,
                                               int* __restrict__ bcnt) {
    __shared__ int h[NBUK];
    int t = threadIdx.x;
    if (t < NBUK) h[t] = 0;
    __syncthreads();
    int base = (blockIdx.x * 256 + t) * 16;
    #pragma unroll
    for (int q = 0; q < 4; ++q) {
        int o = base + 4 * q;
        if (o + 4 <= NE) {
            int4 r4 = *(const int4*)&row[o];
            atomicAdd(&h[r4.x >> BSH], 1);
            atomicAdd(&h[r4.y >> BSH], 1);
            atomicAdd(&h[r4.z >> BSH], 1);
            atomicAdd(&h[r4.w >> BSH], 1);
        }
    }
    __syncthreads();
    if (t < NBUK && h[t] > 0) atomicAdd(&bcnt[t], h[t]);
}

// ---------------- tiny bucket scan ----------------
__global__ void k_bscan(const int* __restrict__ bcnt, int* __restrict__ bbase,
                        int* __restrict__ bcur) {
    if (threadIdx.x == 0) {
        int acc = 0;
        for (int i = 0; i < NBUK; ++i) {
            bbase[i] = acc;
            bcur[i] = acc;
            acc += bcnt[i];
        }
    }
}

// ---------------- P1: partition edges into bucket-grouped pairs ----------
__global__ __launch_bounds__(256) void k_part(const int* __restrict__ row,
                                              const int* __restrict__ col,
                                              int* __restrict__ bcur,
                                              int2* __restrict__ pairs) {
    __shared__ int hist[NBUK];
    __shared__ int loff[NBUK];
    __shared__ int gbase[NBUK];
    __shared__ int2 stage[CHUNK];          // 32 KB
    __shared__ unsigned char bkt[CHUNK];   // 4 KB
    const int t = threadIdx.x;
    const int cb = blockIdx.x * CHUNK;
    const int ccnt = min(CHUNK, NE - cb);
    const int nquad = ccnt >> 2;
    if (t < NBUK) hist[t] = 0;
    __syncthreads();

    int rr[16], cc[16], rk[16];
    #pragma unroll
    for (int j = 0; j < 4; ++j) {
        int q = j * 256 + t;
        if (q < nquad) {
            int4 r4 = *(const int4*)&row[cb + 4 * q];
            int4 c4 = *(const int4*)&col[cb + 4 * q];
            rr[4 * j] = r4.x; rr[4 * j + 1] = r4.y; rr[4 * j + 2] = r4.z; rr[4 * j + 3] = r4.w;
            cc[4 * j] = c4.x; cc[4 * j + 1] = c4.y; cc[4 * j + 2] = c4.z; cc[4 * j + 3] = c4.w;
            #pragma unroll
            for (int k = 0; k < 4; ++k)
                rk[4 * j + k] = atomicAdd(&hist[rr[4 * j + k] >> BSH], 1);
        }
    }
    __syncthreads();
    if (t == 0) {  // exclusive scan over 49 buckets
        int acc = 0;
        for (int i = 0; i < NBUK; ++i) { loff[i] = acc; acc += hist[i]; }
    }
    __syncthreads();
    if (t < NBUK && hist[t] > 0) gbase[t] = atomicAdd(&bcur[t], hist[t]);
    __syncthreads();
    #pragma unroll
    for (int j = 0; j < 4; ++j) {
        int q = j * 256 + t;
        if (q < nquad) {
            #pragma unroll
            for (int k = 0; k < 4; ++k) {
                int b = rr[4 * j + k] >> BSH;
                int pos = loff[b] + rk[4 * j + k];
                stage[pos] = make_int2(rr[4 * j + k], cc[4 * j + k]);
                bkt[pos] = (unsigned char)b;
            }
        }
    }
    __syncthreads();
    for (int s = t; s < ccnt; s += 256) {
        int b = bkt[s];
        pairs[gbase[b] + (s - loff[b])] = stage[s];
    }
}

// ---------------- P2: per-bucket count + scan + scatter ------------------
// One block per bucket. Pass A: LDS degree histogram -> cnt/dinv/rowptr
// (coalesced writes), LDS scan gives cursors (CSR base = bbase[b] since
// buckets are contiguous node ranges). Pass B: scatter csr within the
// bucket's ~130KB L2-resident window. No global atomics anywhere.
__global__ __launch_bounds__(1024) void k_fine(const int* __restrict__ bbase,
                                               const int* __restrict__ bcnt,
                                               const int2* __restrict__ pairs,
                                               int* __restrict__ cnt,
                                               int* __restrict__ rowptr,
                                               float* __restrict__ dinv,
                                               int* __restrict__ csr) {
    __shared__ int h[BNODES];   // counts -> cursors
    __shared__ int sc[1024];    // pair-sum scan
    const int b = blockIdx.x;
    const int nb = b << BSH;
    const int t = threadIdx.x;
    for (int i = t; i < BNODES; i += 1024) h[i] = 0;
    __syncthreads();
    const int st = bbase[b];
    const int en = st + bcnt[b];
    for (int e = st + t; e < en; e += 1024) {
        int2 p = pairs[e];
        atomicAdd(&h[p.x - nb], 1);
    }
    __syncthreads();
    // each thread owns nodes 2t, 2t+1
    int h0 = h[2 * t], h1 = h[2 * t + 1];
    int v = h0 + h1;
    sc[t] = v;
    __syncthreads();
    for (int o = 1; o < 1024; o <<= 1) {
        int a = (t >= o) ? sc[t - o] : 0;
        __syncthreads();
        sc[t] += a;
        __syncthreads();
    }
    int base = st + sc[t] - v;  // absolute CSR offset of node nb+2t
    int n0 = nb + 2 * t, n1 = nb + 2 * t + 1;
    if (n0 < NN) {
        cnt[n0] = h0;
        rowptr[n0] = base;
        dinv[n0] = rsqrtf((float)(h0 + 1));
    }
    if (n1 < NN) {
        cnt[n1] = h1;
        rowptr[n1] = base + h0;
        dinv[n1] = rsqrtf((float)(h1 + 1));
    }
    h[2 * t] = base;           // convert to absolute cursors
    h[2 * t + 1] = base + h0;
    __syncthreads();
    for (int e = st + t; e < en; e += 1024) {
        int2 p = pairs[e];
        int pos = atomicAdd(&h[p.x - nb], 1);
        csr[pos] = p.y;
    }
}

// ---------------- u = dinv * (X @ W) ----------------
#define GEMM_ROWS 64
#define XPAD (NF + 4)

__global__ __launch_bounds__(256) void k_gemm(const float* __restrict__ x,
                                              const float* __restrict__ W,
                                              const float* __restrict__ dinv,
                                              float* __restrict__ u) {
    __shared__ float Wl[NF * NC];
    __shared__ float xs[GEMM_ROWS * XPAD];
    const int t = threadIdx.x;
    for (int i = t; i < NF * NC; i += 256) Wl[i] = W[i];
    const int rbase = blockIdx.x * GEMM_ROWS;
    const float4* x4 = (const float4*)x;
    for (int i = t; i < GEMM_ROWS * (NF / 4); i += 256) {
        int lrow = i / (NF / 4), k4 = i - lrow * (NF / 4);
        int r = rbase + lrow;
        float4 v = (r < NN) ? x4[(size_t)r * (NF / 4) + k4]
                            : make_float4(0.f, 0.f, 0.f, 0.f);
        *(float4*)&xs[lrow * XPAD + 4 * k4] = v;
    }
    __syncthreads();
    const int lr = t >> 2;
    const int cg = t & 3;
    float4 acc = make_float4(0.f, 0.f, 0.f, 0.f);
    #pragma unroll
    for (int k = 0; k < NF; ++k) {
        float xv = xs[lr * XPAD + k];
        float4 w = *(const float4*)&Wl[k * NC + cg * 4];
        acc.x = fmaf(xv, w.x, acc.x);
        acc.y = fmaf(xv, w.y, acc.y);
        acc.z = fmaf(xv, w.z, acc.z);
        acc.w = fmaf(xv, w.w, acc.w);
    }
    int r = rbase + lr;
    if (r < NN) {
        float d = dinv[r];
        acc.x *= d; acc.y *= d; acc.z *= d; acc.w *= d;
        *(float4*)&u[r * NC + cg * 4] = acc;
    }
}

// ---------------- gather hops (no atomics, no weights) ----------------

__global__ __launch_bounds__(256) void k_hop1(const int* __restrict__ rowptr,
                                              const int* __restrict__ cnt,
                                              const float* __restrict__ dinv,
                                              const int* __restrict__ csr,
                                              const float* __restrict__ u,
                                              float* __restrict__ u1) {
    int t = blockIdx.x * 256 + threadIdx.x;  // exact grid NN*NC
    int n = t >> 4, c = t & 15;
    int s = rowptr[n], m = cnt[n];
    float acc = u[(n << 4) + c];
    int i = 0;
    for (; i + 8 <= m; i += 8) {
        int cc[8];
        #pragma unroll
        for (int j = 0; j < 8; ++j) cc[j] = __builtin_nontemporal_load(&csr[s + i + j]);
        float a0 = u[(cc[0] << 4) + c], a1 = u[(cc[1] << 4) + c];
        float a2 = u[(cc[2] << 4) + c], a3 = u[(cc[3] << 4) + c];
        float a4 = u[(cc[4] << 4) + c], a5 = u[(cc[5] << 4) + c];
        float a6 = u[(cc[6] << 4) + c], a7 = u[(cc[7] << 4) + c];
        acc += ((a0 + a1) + (a2 + a3)) + ((a4 + a5) + (a6 + a7));
    }
    for (; i < m; ++i) acc += u[(__builtin_nontemporal_load(&csr[s + i]) << 4) + c];
    float d = dinv[n];
    u1[t] = d * d * acc;
}

__global__ __launch_bounds__(256) void k_hop2(const int* __restrict__ rowptr,
                                              const int* __restrict__ cnt,
                                              const float* __restrict__ dinv,
                                              const int* __restrict__ csr,
                                              const float* __restrict__ u1,
                                              const float* __restrict__ bias,
                                              float* __restrict__ out) {
    int t = blockIdx.x * 256 + threadIdx.x;  // exact grid NN*NC
    int n = t >> 4, c = t & 15;
    int s = rowptr[n], m = cnt[n];
    float acc = u1[(n << 4) + c];
    int i = 0;
    for (; i + 8 <= m; i += 8) {
        int cc[8];
        #pragma unroll
        for (int j = 0; j < 8; ++j) cc[j] = __builtin_nontemporal_load(&csr[s + i + j]);
        float a0 = u1[(cc[0] << 4) + c], a1 = u1[(cc[1] << 4) + c];
        float a2 = u1[(cc[2] << 4) + c], a3 = u1[(cc[3] << 4) + c];
        float a4 = u1[(cc[4] << 4) + c], a5 = u1[(cc[5] << 4) + c];
        float a6 = u1[(cc[6] << 4) + c], a7 = u1[(cc[7] << 4) + c];
        acc += ((a0 + a1) + (a2 + a3)) + ((a4 + a5) + (a6 + a7));
    }
    for (; i < m; ++i) acc += u1[(__builtin_nontemporal_load(&csr[s + i]) << 4) + c];
    float v = dinv[n] * acc + bias[c];
    float mx = v;
    #pragma unroll
    for (int o = 8; o > 0; o >>= 1) mx = fmaxf(mx, __shfl_xor(mx, o, 16));
    float ex = expf(v - mx);
    float sm = ex;
    #pragma unroll
    for (int o = 8; o > 0; o >>= 1) sm += __shfl_xor(sm, o, 16);
    out[t] = v - mx - logf(sm);
}

extern "C" void kernel_launch(void* const* d_in, const int* in_sizes, int n_in,
                              void* d_out, int out_size, void* d_ws, size_t ws_size,
                              hipStream_t stream) {
    const float* x    = (const float*)d_in[0];
    const int*   ei   = (const int*)d_in[1];
    const float* W    = (const float*)d_in[2];
    const float* bias = (const float*)d_in[3];
    float* out = (float*)d_out;

    const int* row = ei;       // destinations
    const int* col = ei + NE;  // sources

    char* ws = (char*)d_ws;
    size_t off = 0;
    auto carve = [&](size_t bytes) -> void* {
        void* p = ws + off;
        off += (bytes + 255) & ~(size_t)255;
        return p;
    };
    int*   cnt    = (int*)  carve((size_t)NN * sizeof(int));
    float* dinv   = (float*)carve((size_t)NN * sizeof(float));
    int*   rowptr = (int*)  carve((size_t)NN * sizeof(int));
    int*   bcnt   = (int*)  carve((size_t)NBUK * sizeof(int));
    int*   bbase  = (int*)  carve((size_t)NBUK * sizeof(int));
    int*   bcur   = (int*)  carve((size_t)NBUK * sizeof(int));
    int2*  pairs  = (int2*) carve((size_t)NE * sizeof(int2));   // 12.8 MB
    int*   csr    = (int*)  carve((size_t)NE * sizeof(int));    // 6.4 MB
    // u / u1 alias pairs (dead after k_fine; gemm runs after)
    float* u  = (float*)pairs;
    float* u1 = (float*)pairs + (size_t)NN * NC;

    const int EB16 = (NE / 16 + 255) / 256;  // 391

    k_zero <<<1, 64, 0, stream>>>(bcnt);
    k_bhist<<<EB16, 256, 0, stream>>>(row, bcnt);
    k_bscan<<<1, 64, 0, stream>>>(bcnt, bbase, bcur);
    k_part <<<P1B, 256, 0, stream>>>(row, col, bcur, pairs);
    k_fine <<<NBUK, 1024, 0, stream>>>(bbase, bcnt, pairs, cnt, rowptr, dinv, csr);

    k_gemm<<<(NN + GEMM_ROWS - 1) / GEMM_ROWS, 256, 0, stream>>>(x, W, dinv, u);

    k_hop1<<<(NN * NC) / 256, 256, 0, stream>>>(rowptr, cnt, dinv, csr, u, u1);
    k_hop2<<<(NN * NC) / 256, 256, 0, stream>>>(rowptr, cnt, dinv, csr, u1, bias, out);
}

// Round 6
// 145.513 us; speedup vs baseline: 2.1448x; 1.2045x over previous
//
#include <hip/hip_runtime.h>
#include <math.h>

#define NN 100000   // nodes
#define NE 1600000  // edges
#define NF 128      // in features
#define NC 16       // classes
#define NBUK 391    // buckets = ceil(NN/256)
#define BSH 8       // bucket = row >> 8
#define BNODES 256  // nodes per bucket
#define MAXEDG 6144 // cap on edges/bucket (mean 4092, std 64 -> 32 sigma)
#define CHUNK 4096  // edges per partition block
#define P1B 391     // ceil(NE/CHUNK)

// ---------------- zero bucket counters ----------------
__global__ void k_zero(int* __restrict__ bcnt) {
    int n = threadIdx.x;
    if (n < NBUK) bcnt[n] = 0;
}

// ---------------- P0: bucket histogram (16 edges/thread) ----------------
__global__ __launch_bounds__(256) void k_bhist(const int* __restrict__ row,
                                               int* __restrict__ bcnt) {
    __shared__ int h[NBUK];
    int t = threadIdx.x;
    for (int i = t; i < NBUK; i += 256) h[i] = 0;
    __syncthreads();
    int base = (blockIdx.x * 256 + t) * 16;
    #pragma unroll
    for (int q = 0; q < 4; ++q) {
        int o = base + 4 * q;
        if (o + 4 <= NE) {
            int4 r4 = *(const int4*)&row[o];
            atomicAdd(&h[r4.x >> BSH], 1);
            atomicAdd(&h[r4.y >> BSH], 1);
            atomicAdd(&h[r4.z >> BSH], 1);
            atomicAdd(&h[r4.w >> BSH], 1);
        }
    }
    __syncthreads();
    for (int i = t; i < NBUK; i += 256)
        if (h[i] > 0) atomicAdd(&bcnt[i], h[i]);
}

// ---------------- bucket scan (1 wave, shuffle scan) ----------------
__global__ void k_bscan(const int* __restrict__ bcnt, int* __restrict__ bbase,
                        int* __restrict__ bcur) {
    int t = threadIdx.x;  // 64 threads, lane t owns buckets 7t..7t+6
    int loc[7];
    int acc = 0;
    #pragma unroll
    for (int j = 0; j < 7; ++j) {
        int idx = t * 7 + j;
        int v = (idx < NBUK) ? bcnt[idx] : 0;
        loc[j] = acc;
        acc += v;
    }
    int s = acc;
    #pragma unroll
    for (int o = 1; o < 64; o <<= 1) {
        int u = __shfl_up(s, o, 64);
        if (t >= o) s += u;
    }
    int excl = s - acc;
    #pragma unroll
    for (int j = 0; j < 7; ++j) {
        int idx = t * 7 + j;
        if (idx < NBUK) {
            bbase[idx] = excl + loc[j];
            bcur[idx] = excl + loc[j];
        }
    }
}

// ---------------- P1: partition edges into bucket-grouped pairs ----------
__global__ __launch_bounds__(256) void k_part(const int* __restrict__ row,
                                              const int* __restrict__ col,
                                              int* __restrict__ bcur,
                                              int2* __restrict__ pairs) {
    __shared__ int hist[NBUK];
    __shared__ int loff[NBUK];
    __shared__ int gbase[NBUK];
    __shared__ int2 stage[CHUNK];            // 32 KB
    __shared__ unsigned short bkt[CHUNK];    // 8 KB
    const int t = threadIdx.x;
    const int cb = blockIdx.x * CHUNK;
    const int ccnt = min(CHUNK, NE - cb);
    const int nquad = ccnt >> 2;
    for (int i = t; i < NBUK; i += 256) hist[i] = 0;
    __syncthreads();

    int rr[16], cc[16], rk[16];
    #pragma unroll
    for (int j = 0; j < 4; ++j) {
        int q = j * 256 + t;
        if (q < nquad) {
            int4 r4 = *(const int4*)&row[cb + 4 * q];
            int4 c4 = *(const int4*)&col[cb + 4 * q];
            rr[4 * j] = r4.x; rr[4 * j + 1] = r4.y; rr[4 * j + 2] = r4.z; rr[4 * j + 3] = r4.w;
            cc[4 * j] = c4.x; cc[4 * j + 1] = c4.y; cc[4 * j + 2] = c4.z; cc[4 * j + 3] = c4.w;
            #pragma unroll
            for (int k = 0; k < 4; ++k)
                rk[4 * j + k] = atomicAdd(&hist[rr[4 * j + k] >> BSH], 1);
        }
    }
    __syncthreads();
    if (t < 64) {  // wave-parallel exclusive scan over 391 buckets
        int loc[7];
        int acc = 0;
        #pragma unroll
        for (int j = 0; j < 7; ++j) {
            int idx = t * 7 + j;
            int v = (idx < NBUK) ? hist[idx] : 0;
            loc[j] = acc;
            acc += v;
        }
        int s = acc;
        #pragma unroll
        for (int o = 1; o < 64; o <<= 1) {
            int u = __shfl_up(s, o, 64);
            if (t >= o) s += u;
        }
        int excl = s - acc;
        #pragma unroll
        for (int j = 0; j < 7; ++j) {
            int idx = t * 7 + j;
            if (idx < NBUK) loff[idx] = excl + loc[j];
        }
    }
    __syncthreads();
    for (int i = t; i < NBUK; i += 256)
        if (hist[i] > 0) gbase[i] = atomicAdd(&bcur[i], hist[i]);
    __syncthreads();
    #pragma unroll
    for (int j = 0; j < 4; ++j) {
        int q = j * 256 + t;
        if (q < nquad) {
            #pragma unroll
            for (int k = 0; k < 4; ++k) {
                int b = rr[4 * j + k] >> BSH;
                int pos = loff[b] + rk[4 * j + k];
                stage[pos] = make_int2(rr[4 * j + k], cc[4 * j + k]);
                bkt[pos] = (unsigned short)b;
            }
        }
    }
    __syncthreads();
    for (int s = t; s < ccnt; s += 256) {
        int b = bkt[s];
        pairs[gbase[b] + (s - loff[b])] = stage[s];
    }
}

// ---------------- P2: per-bucket LDS counting sort -> cnt/rowptr/dinv/csr --
// One 256-thread block per 256-node bucket. Single read of pairs (staged
// packed in LDS), 256-entry histogram + scan, scatter csr within a 16KB
// single-block-owned window (L2-merged). No global atomics.
__global__ __launch_bounds__(256) void k_fine(const int* __restrict__ bbase,
                                              const int* __restrict__ bcnt,
                                              const int2* __restrict__ pairs,
                                              int* __restrict__ cnt,
                                              int* __restrict__ rowptr,
                                              float* __restrict__ dinv,
                                              int* __restrict__ csr) {
    __shared__ int colk[MAXEDG];  // (key<<20)|col ; col<2^17
    __shared__ int h[BNODES];     // hist -> cursor
    __shared__ int hs[BNODES];    // scan temp
    const int b = blockIdx.x;
    const int nb = b << BSH;
    const int t = threadIdx.x;
    h[t] = 0;
    __syncthreads();
    const int st = bbase[b];
    const int m = bcnt[b];
    for (int i = t; i < m; i += 256) {
        int2 p = pairs[st + i];
        int key = p.x & (BNODES - 1);
        atomicAdd(&h[key], 1);
        colk[i] = (key << 20) | p.y;
    }
    __syncthreads();
    int v = h[t];
    hs[t] = v;
    __syncthreads();
    for (int o = 1; o < 256; o <<= 1) {
        int a = (t >= o) ? hs[t - o] : 0;
        __syncthreads();
        hs[t] += a;
        __syncthreads();
    }
    int excl = hs[t] - v;
    int n0 = nb + t;
    if (n0 < NN) {
        cnt[n0] = v;
        rowptr[n0] = st + excl;
        dinv[n0] = rsqrtf((float)(v + 1));
    }
    h[t] = excl;  // local cursor
    __syncthreads();
    for (int i = t; i < m; i += 256) {
        int pk = colk[i];
        int pos = atomicAdd(&h[pk >> 20], 1);
        csr[st + pos] = pk & 0xFFFFF;
    }
}

// ---------------- u = dinv * (X @ W) ----------------
#define GEMM_ROWS 64
#define XPAD (NF + 4)

__global__ __launch_bounds__(256) void k_gemm(const float* __restrict__ x,
                                              const float* __restrict__ W,
                                              const float* __restrict__ dinv,
                                              float* __restrict__ u) {
    __shared__ float Wl[NF * NC];
    __shared__ float xs[GEMM_ROWS * XPAD];
    const int t = threadIdx.x;
    for (int i = t; i < NF * NC; i += 256) Wl[i] = W[i];
    const int rbase = blockIdx.x * GEMM_ROWS;
    const float4* x4 = (const float4*)x;
    for (int i = t; i < GEMM_ROWS * (NF / 4); i += 256) {
        int lrow = i / (NF / 4), k4 = i - lrow * (NF / 4);
        int r = rbase + lrow;
        float4 v = (r < NN) ? x4[(size_t)r * (NF / 4) + k4]
                            : make_float4(0.f, 0.f, 0.f, 0.f);
        *(float4*)&xs[lrow * XPAD + 4 * k4] = v;
    }
    __syncthreads();
    const int lr = t >> 2;
    const int cg = t & 3;
    float4 acc = make_float4(0.f, 0.f, 0.f, 0.f);
    #pragma unroll
    for (int k = 0; k < NF; ++k) {
        float xv = xs[lr * XPAD + k];
        float4 w = *(const float4*)&Wl[k * NC + cg * 4];
        acc.x = fmaf(xv, w.x, acc.x);
        acc.y = fmaf(xv, w.y, acc.y);
        acc.z = fmaf(xv, w.z, acc.z);
        acc.w = fmaf(xv, w.w, acc.w);
    }
    int r = rbase + lr;
    if (r < NN) {
        float d = dinv[r];
        acc.x *= d; acc.y *= d; acc.z *= d; acc.w *= d;
        *(float4*)&u[r * NC + cg * 4] = acc;
    }
}

// ---------------- gather hops (no atomics, no weights) ----------------

__global__ __launch_bounds__(256) void k_hop1(const int* __restrict__ rowptr,
                                              const int* __restrict__ cnt,
                                              const float* __restrict__ dinv,
                                              const int* __restrict__ csr,
                                              const float* __restrict__ u,
                                              float* __restrict__ u1) {
    int t = blockIdx.x * 256 + threadIdx.x;  // exact grid NN*NC
    int n = t >> 4, c = t & 15;
    int s = rowptr[n], m = cnt[n];
    float acc = u[(n << 4) + c];
    int i = 0;
    for (; i + 8 <= m; i += 8) {
        int cc[8];
        #pragma unroll
        for (int j = 0; j < 8; ++j) cc[j] = __builtin_nontemporal_load(&csr[s + i + j]);
        float a0 = u[(cc[0] << 4) + c], a1 = u[(cc[1] << 4) + c];
        float a2 = u[(cc[2] << 4) + c], a3 = u[(cc[3] << 4) + c];
        float a4 = u[(cc[4] << 4) + c], a5 = u[(cc[5] << 4) + c];
        float a6 = u[(cc[6] << 4) + c], a7 = u[(cc[7] << 4) + c];
        acc += ((a0 + a1) + (a2 + a3)) + ((a4 + a5) + (a6 + a7));
    }
    for (; i < m; ++i) acc += u[(__builtin_nontemporal_load(&csr[s + i]) << 4) + c];
    float d = dinv[n];
    u1[t] = d * d * acc;
}

__global__ __launch_bounds__(256) void k_hop2(const int* __restrict__ rowptr,
                                              const int* __restrict__ cnt,
                                              const float* __restrict__ dinv,
                                              const int* __restrict__ csr,
                                              const float* __restrict__ u1,
                                              const float* __restrict__ bias,
                                              float* __restrict__ out) {
    int t = blockIdx.x * 256 + threadIdx.x;  // exact grid NN*NC
    int n = t >> 4, c = t & 15;
    int s = rowptr[n], m = cnt[n];
    float acc = u1[(n << 4) + c];
    int i = 0;
    for (; i + 8 <= m; i += 8) {
        int cc[8];
        #pragma unroll
        for (int j = 0; j < 8; ++j) cc[j] = __builtin_nontemporal_load(&csr[s + i + j]);
        float a0 = u1[(cc[0] << 4) + c], a1 = u1[(cc[1] << 4) + c];
        float a2 = u1[(cc[2] << 4) + c], a3 = u1[(cc[3] << 4) + c];
        float a4 = u1[(cc[4] << 4) + c], a5 = u1[(cc[5] << 4) + c];
        float a6 = u1[(cc[6] << 4) + c], a7 = u1[(cc[7] << 4) + c];
        acc += ((a0 + a1) + (a2 + a3)) + ((a4 + a5) + (a6 + a7));
    }
    for (; i < m; ++i) acc += u1[(__builtin_nontemporal_load(&csr[s + i]) << 4) + c];
    float v = dinv[n] * acc + bias[c];
    float mx = v;
    #pragma unroll
    for (int o = 8; o > 0; o >>= 1) mx = fmaxf(mx, __shfl_xor(mx, o, 16));
    float ex = expf(v - mx);
    float sm = ex;
    #pragma unroll
    for (int o = 8; o > 0; o >>= 1) sm += __shfl_xor(sm, o, 16);
    out[t] = v - mx - logf(sm);
}

extern "C" void kernel_launch(void* const* d_in, const int* in_sizes, int n_in,
                              void* d_out, int out_size, void* d_ws, size_t ws_size,
                              hipStream_t stream) {
    const float* x    = (const float*)d_in[0];
    const int*   ei   = (const int*)d_in[1];
    const float* W    = (const float*)d_in[2];
    const float* bias = (const float*)d_in[3];
    float* out = (float*)d_out;

    const int* row = ei;       // destinations
    const int* col = ei + NE;  // sources

    char* ws = (char*)d_ws;
    size_t off = 0;
    auto carve = [&](size_t bytes) -> void* {
        void* p = ws + off;
        off += (bytes + 255) & ~(size_t)255;
        return p;
    };
    int*   cnt    = (int*)  carve((size_t)NN * sizeof(int));
    float* dinv   = (float*)carve((size_t)NN * sizeof(float));
    int*   rowptr = (int*)  carve((size_t)NN * sizeof(int));
    int*   bcnt   = (int*)  carve((size_t)NBUK * sizeof(int));
    int*   bbase  = (int*)  carve((size_t)NBUK * sizeof(int));
    int*   bcur   = (int*)  carve((size_t)NBUK * sizeof(int));
    int2*  pairs  = (int2*) carve((size_t)NE * sizeof(int2));   // 12.8 MB
    int*   csr    = (int*)  carve((size_t)NE * sizeof(int));    // 6.4 MB
    // u / u1 alias pairs (dead after k_fine; gemm runs after)
    float* u  = (float*)pairs;
    float* u1 = (float*)pairs + (size_t)NN * NC;

    const int EB16 = (NE / 16 + 255) / 256;  // 391

    k_zero <<<1, 512, 0, stream>>>(bcnt);
    k_bhist<<<EB16, 256, 0, stream>>>(row, bcnt);
    k_bscan<<<1, 64, 0, stream>>>(bcnt, bbase, bcur);
    k_part <<<P1B, 256, 0, stream>>>(row, col, bcur, pairs);
    k_fine <<<NBUK, 256, 0, stream>>>(bbase, bcnt, pairs, cnt, rowptr, dinv, csr);

    k_gemm<<<(NN + GEMM_ROWS - 1) / GEMM_ROWS, 256, 0, stream>>>(x, W, dinv, u);

    k_hop1<<<(NN * NC) / 256, 256, 0, stream>>>(rowptr, cnt, dinv, csr, u, u1);
    k_hop2<<<(NN * NC) / 256, 256, 0, stream>>>(rowptr, cnt, dinv, csr, u1, bias, out);
}